// Round 3
// baseline (8356.525 us; speedup 1.0000x reference)
//
#include <hip/hip_runtime.h>

typedef __bf16 bf16;
typedef bf16 bf16x8 __attribute__((ext_vector_type(8)));
typedef float f32x4 __attribute__((ext_vector_type(4)));

#define AS1 __attribute__((address_space(1)))
#define AS3 __attribute__((address_space(3)))

#define B_ 2048
#define T_ 80
#define E_ 100
#define H_ 512
#define TC_ 16              // time-chunk
#define NC_ (T_ / TC_)      // 5 chunks
#define ROWS_ 32            // batch rows per rnn block
#define LSTR_ 520           // LDS row stride (bf16 elems): 16B-aligned, 4-way-max banks

// Layout: SEQ is TIME-MAJOR: seq[(t*B_ + b)*H_ + h]

__device__ __forceinline__ float fast_tanh(float x) {
  float e = exp2f(x * 2.8853900817779268f);  // e^{2x}
  return 1.f - 2.f * __builtin_amdgcn_rcpf(e + 1.f);
}

// dst[n*Kp + k] = k<K ? src[k*N + n] : 0   (transpose to [N][Kp], bf16, zero-pad K)
__global__ void convert_weight(const float* __restrict__ src, bf16* __restrict__ dst,
                               int K, int Kp, int N) {
  int idx = blockIdx.x * 256 + threadIdx.x;
  if (idx >= N * Kp) return;
  int n = idx / Kp, k = idx - n * Kp;
  float v = (k < K) ? src[(long)k * N + n] : 0.f;
  dst[idx] = (bf16)v;
}

// C[128-row tile] = A @ Bt^T; A pre-offset to chunk start. Grid (TC_*B_/128, 4), 256 thr.
__global__ __launch_bounds__(256) void gemm_bf16(
    const bf16* __restrict__ A, const bf16* __restrict__ Bt, bf16* __restrict__ C, int K) {
  __shared__ bf16 As[128 * 32];
  __shared__ bf16 Bs[128 * 32];
  const int tid = threadIdx.x;
  const int wave = tid >> 6, lane = tid & 63;
  const int l = lane & 15, q = lane >> 4;
  const long m0 = (long)blockIdx.x * 128;
  const int n0 = blockIdx.y * 128;
  const int wm = (wave >> 1) * 64, wn = (wave & 1) * 64;

  f32x4 acc[4][4] = {};

  const int e0 = tid, e1 = 256 + tid;
  const int r0 = e0 >> 2, c0 = e0 & 3;
  const int r1 = e1 >> 2, c1 = e1 & 3;
  const int s0 = c0 ^ (r0 & 3) ^ ((r0 >> 2) & 3);
  const int s1 = c1 ^ (r1 & 3) ^ ((r1 >> 2) & 3);
  const int swr = q ^ (l & 3) ^ ((l >> 2) & 3);

  const bf16* A0 = A + (m0 + r0) * K + s0 * 8;
  const bf16* A1 = A + (m0 + r1) * K + s1 * 8;
  const bf16* B0 = Bt + (long)(n0 + r0) * K + s0 * 8;
  const bf16* B1 = Bt + (long)(n0 + r1) * K + s1 * 8;
  bf16* AsW0 = As + (wave * 64) * 8;
  bf16* AsW1 = As + (256 + wave * 64) * 8;
  bf16* BsW0 = Bs + (wave * 64) * 8;
  bf16* BsW1 = Bs + (256 + wave * 64) * 8;

  for (int k0 = 0; k0 < K; k0 += 32) {
    __builtin_amdgcn_global_load_lds((const AS1 void*)(A0 + k0), (AS3 void*)AsW0, 16, 0, 0);
    __builtin_amdgcn_global_load_lds((const AS1 void*)(A1 + k0), (AS3 void*)AsW1, 16, 0, 0);
    __builtin_amdgcn_global_load_lds((const AS1 void*)(B0 + k0), (AS3 void*)BsW0, 16, 0, 0);
    __builtin_amdgcn_global_load_lds((const AS1 void*)(B1 + k0), (AS3 void*)BsW1, 16, 0, 0);
    __syncthreads();
    bf16x8 af[4], bfm[4];
#pragma unroll
    for (int i = 0; i < 4; i++) {
      af[i]  = *(const bf16x8*)(As + (wm + i * 16 + l) * 32 + swr * 8);
      bfm[i] = *(const bf16x8*)(Bs + (wn + i * 16 + l) * 32 + swr * 8);
    }
#pragma unroll
    for (int i = 0; i < 4; i++)
#pragma unroll
      for (int j = 0; j < 4; j++)
        acc[i][j] = __builtin_amdgcn_mfma_f32_16x16x32_bf16(af[i], bfm[j], acc[i][j], 0, 0, 0);
    __syncthreads();
  }
#pragma unroll
  for (int i = 0; i < 4; i++)
#pragma unroll
    for (int j = 0; j < 4; j++)
#pragma unroll
      for (int r = 0; r < 4; r++)
        C[(m0 + wm + i * 16 + q * 4 + r) * (long)H_ + n0 + wn + j * 16 + l] =
            (bf16)acc[i][j][r];
}

// Layer-1 GEMM with fused embedding gather: C = emb[tokens] @ W1 (K padded to 128).
__global__ __launch_bounds__(256) void gemm1_embed(
    const int* __restrict__ tokens, const float* __restrict__ emb,
    const bf16* __restrict__ Bt, bf16* __restrict__ xwc, int t0) {
  __shared__ bf16 As[128 * 32];
  __shared__ bf16 Bs[128 * 32];
  __shared__ int stok[128];
  const int tid = threadIdx.x;
  const int wave = tid >> 6, lane = tid & 63;
  const int l = lane & 15, q = lane >> 4;
  const int trow = blockIdx.x >> 4;
  const int b0 = (blockIdx.x & 15) * 128;
  const int t = t0 + trow;
  const int n0 = blockIdx.y * 128;
  const int wm = (wave >> 1) * 64, wn = (wave & 1) * 64;
  const int K = 128;

  if (tid < 128) stok[tid] = tokens[(b0 + tid) * T_ + t];
  __syncthreads();

  f32x4 acc[4][4] = {};

  const int e0 = tid, e1 = 256 + tid;
  const int r0 = e0 >> 2, c0 = e0 & 3;
  const int r1 = e1 >> 2, c1 = e1 & 3;
  const int s0 = c0 ^ (r0 & 3) ^ ((r0 >> 2) & 3);
  const int s1 = c1 ^ (r1 & 3) ^ ((r1 >> 2) & 3);
  const int swr = q ^ (l & 3) ^ ((l >> 2) & 3);

  const bf16* B0 = Bt + (long)(n0 + r0) * K + s0 * 8;
  const bf16* B1 = Bt + (long)(n0 + r1) * K + s1 * 8;
  bf16* BsW0 = Bs + (wave * 64) * 8;
  bf16* BsW1 = Bs + (256 + wave * 64) * 8;

  const int ar = tid >> 1, hh = tid & 1;
  const int asw = (ar & 3) ^ ((ar >> 2) & 3);
  const float* er = emb + (long)stok[ar] * E_;

  for (int k0 = 0; k0 < K; k0 += 32) {
    __builtin_amdgcn_global_load_lds((const AS1 void*)(B0 + k0), (AS3 void*)BsW0, 16, 0, 0);
    __builtin_amdgcn_global_load_lds((const AS1 void*)(B1 + k0), (AS3 void*)BsW1, 16, 0, 0);
    bf16x8 v[2];
#pragma unroll
    for (int cch = 0; cch < 2; cch++) {
      int kb = k0 + hh * 16 + cch * 8;
#pragma unroll
      for (int j = 0; j < 8; j++) {
        int k = kb + j;
        v[cch][j] = (bf16)((k < E_) ? er[k] : 0.f);
      }
    }
    *(bf16x8*)(As + ar * 32 + ((2 * hh + 0) ^ asw) * 8) = v[0];
    *(bf16x8*)(As + ar * 32 + ((2 * hh + 1) ^ asw) * 8) = v[1];
    __syncthreads();
    bf16x8 af[4], bfm[4];
#pragma unroll
    for (int i = 0; i < 4; i++) {
      af[i]  = *(const bf16x8*)(As + (wm + i * 16 + l) * 32 + swr * 8);
      bfm[i] = *(const bf16x8*)(Bs + (wn + i * 16 + l) * 32 + swr * 8);
    }
#pragma unroll
    for (int i = 0; i < 4; i++)
#pragma unroll
      for (int j = 0; j < 4; j++)
        acc[i][j] = __builtin_amdgcn_mfma_f32_16x16x32_bf16(af[i], bfm[j], acc[i][j], 0, 0, 0);
    __syncthreads();
  }
  bf16* C = xwc + ((long)trow * B_ + b0) * H_;
#pragma unroll
  for (int i = 0; i < 4; i++)
#pragma unroll
    for (int j = 0; j < 4; j++)
#pragma unroll
      for (int r = 0; r < 4; r++)
        C[(long)(wm + i * 16 + q * 4 + r) * H_ + n0 + wn + j * 16 + l] =
            (bf16)acc[i][j][r];
}

// Recurrent chunk: 64 blocks x 1024 thr; block owns 32 batch rows for TC_ steps.
// 16 waves = 2 row-groups x 8 col-slices (64 cols each). U streamed from L2 (reg-
// pipelined, dist 2); xw staged to LDS via async global_load_lds (prefetch dist 2);
// seq stores routed through LDS -> coalesced 1KB/wave.
__global__ __launch_bounds__(1024, 4) void rnn_chunk(
    const bf16* __restrict__ xwc, const bf16* __restrict__ Ut,
    const float* __restrict__ bias, bf16* __restrict__ seq, int t0, int first) {
  __shared__ bf16 hls[ROWS_ * LSTR_];       // 33.3 KB
  __shared__ bf16 xws[2 * ROWS_ * LSTR_];   // 66.6 KB
  const int tid = threadIdx.x;
  const int wave = tid >> 6, lane = tid & 63;
  const int l = lane & 15, q = lane >> 4;
  const int rg = wave >> 3;   // row-group 0/1 (16 rows each)
  const int ws = wave & 7;    // col-slice (64 cols)
  const int b0 = blockIdx.x * ROWS_;

  // init h_{t0-1}: zeros (first chunk) or seq row t0-1; wide, coalesced
  {
    const bf16* hsrc = seq + ((long)(t0 - 1) * B_ + b0) * H_;
    bf16x8 zv;
#pragma unroll
    for (int j = 0; j < 8; j++) zv[j] = (bf16)0.f;
#pragma unroll
    for (int cc = 0; cc < 2; cc++) {
      int m = wave + cc * 16;          // one row per wave per pass
      bf16x8 v = first ? zv : *(const bf16x8*)(hsrc + (long)m * H_ + lane * 8);
      *(bf16x8*)(hls + m * LSTR_ + lane * 8) = v;
    }
  }

  float bb[4];
#pragma unroll
  for (int nt = 0; nt < 4; nt++) bb[nt] = bias[ws * 64 + nt * 16 + l];

  // async xw prefetch: wave issues rows {2*wave, 2*wave+1}; dest wave-uniform, lane*16B
  auto prefetch = [&](int tl, int buf) {
#pragma unroll
    for (int rr = 0; rr < 2; rr++) {
      int row = wave * 2 + rr;
      __builtin_amdgcn_global_load_lds(
          (const AS1 void*)(xwc + ((long)tl * B_ + b0 + row) * H_ + lane * 8),
          (AS3 void*)(xws + (buf * ROWS_ + row) * LSTR_), 16, 0, 0);
    }
  };

  prefetch(0, 0);
  prefetch(1, 1);
  __syncthreads();  // drains vmcnt: xws[0..1] ready, hls init visible

  const bf16* hb = hls + (rg * 16 + l) * LSTR_ + q * 8;
  const bf16* Ub = Ut + (ws * 64 + l) * H_ + q * 8;

  for (int tl = 0; tl < TC_; tl++) {
    const int cur = tl & 1;
    // acc init from LDS-staged xw (scalar u16 reads, <=4-way banks)
    const bf16* xrow = xws + (cur * ROWS_ + rg * 16 + q * 4) * LSTR_ + ws * 64 + l;
    f32x4 acc[4];
#pragma unroll
    for (int nt = 0; nt < 4; nt++)
#pragma unroll
      for (int r = 0; r < 4; r++)
        acc[nt][r] = (float)xrow[r * LSTR_ + nt * 16] + bb[nt];

    // acc += h_prev @ U ; U from L2, register-pipelined distance 2
    bf16x8 bfr[2][4];
#pragma unroll
    for (int nt = 0; nt < 4; nt++) bfr[0][nt] = *(const bf16x8*)(Ub + nt * 16 * H_);
#pragma unroll
    for (int nt = 0; nt < 4; nt++) bfr[1][nt] = *(const bf16x8*)(Ub + nt * 16 * H_ + 32);
#pragma unroll
    for (int kk = 0; kk < 16; kk++) {
      const int c2 = kk & 1;
      bf16x8 a = *(const bf16x8*)(hb + kk * 32);
#pragma unroll
      for (int nt = 0; nt < 4; nt++)
        acc[nt] = __builtin_amdgcn_mfma_f32_16x16x32_bf16(a, bfr[c2][nt], acc[nt], 0, 0, 0);
      if (kk < 14) {
#pragma unroll
        for (int nt = 0; nt < 4; nt++)
          bfr[c2][nt] = *(const bf16x8*)(Ub + nt * 16 * H_ + (kk + 2) * 32);
      }
    }
    __syncthreads();  // barrier1: all hls/xws reads for step tl done

    // h_new -> hls (fragment layout scalar LDS writes)
#pragma unroll
    for (int nt = 0; nt < 4; nt++)
#pragma unroll
      for (int r = 0; r < 4; r++)
        hls[(rg * 16 + q * 4 + r) * LSTR_ + ws * 64 + nt * 16 + l] =
            (bf16)fast_tanh(acc[nt][r]);
    __syncthreads();  // barrier2: hls updated

    // prefetch xw for step tl+2 into the buffer just consumed (drains at next barrier1)
    if (tl + 2 < TC_) prefetch(tl + 2, cur);

    // coalesced store of step tl's h: wave reads one hls row wide, stores 1KB contiguous
    bf16* sp = seq + ((long)(t0 + tl) * B_ + b0) * H_;
#pragma unroll
    for (int cc = 0; cc < 2; cc++) {
      int m = wave + cc * 16;
      *(bf16x8*)(sp + (long)m * H_ + lane * 8) =
          *(const bf16x8*)(hls + m * LSTR_ + lane * 8);
    }
  }
}

// out[b] = sigmoid(dot(seq[(T-1)*B + b, :], Wo) + bo); one wave per row
__global__ __launch_bounds__(256) void head_kernel(
    const bf16* __restrict__ seq, const float* __restrict__ Wo,
    const float* __restrict__ bo, float* __restrict__ out) {
  int wave = threadIdx.x >> 6, lane = threadIdx.x & 63;
  int row = blockIdx.x * 4 + wave;
  const bf16* p = seq + ((long)(T_ - 1) * B_ + row) * H_ + lane * 8;
  bf16x8 v = *(const bf16x8*)p;
  float s = 0.f;
#pragma unroll
  for (int i = 0; i < 8; i++) s += (float)v[i] * Wo[lane * 8 + i];
#pragma unroll
  for (int off = 32; off; off >>= 1) s += __shfl_down(s, off, 64);
  if (lane == 0) {
    float x = s + bo[0];
    out[row] = 1.f / (1.f + exp2f(-x * 1.44269504088896f));
  }
}

extern "C" void kernel_launch(void* const* d_in, const int* in_sizes, int n_in,
                              void* d_out, int out_size, void* d_ws, size_t ws_size,
                              hipStream_t stream) {
  (void)in_sizes; (void)n_in; (void)out_size; (void)ws_size;
  const int*   tokens = (const int*)d_in[0];
  const float* emb = (const float*)d_in[1];
  const float* W1 = (const float*)d_in[2];
  const float* U1 = (const float*)d_in[3];
  const float* b1 = (const float*)d_in[4];
  const float* W2 = (const float*)d_in[5];
  const float* U2 = (const float*)d_in[6];
  const float* b2 = (const float*)d_in[7];
  const float* W3 = (const float*)d_in[8];
  const float* U3 = (const float*)d_in[9];
  const float* b3 = (const float*)d_in[10];
  const float* W4 = (const float*)d_in[11];
  const float* U4 = (const float*)d_in[12];
  const float* b4 = (const float*)d_in[13];
  const float* Wo = (const float*)d_in[14];
  const float* bo = (const float*)d_in[15];
  float* out = (float*)d_out;

  // ws: SEQ [T_*B_, H_] bf16 (time-major, in-place across layers) | XWC [TC_*B_, H_] | weights
  char* w = (char*)d_ws;
  const size_t SEQ_BYTES = (size_t)T_ * B_ * H_ * 2;   // 160 MB
  const size_t XWC_BYTES = (size_t)TC_ * B_ * H_ * 2;  // 32 MB
  bf16* SEQ = (bf16*)w;
  bf16* XWC = (bf16*)(w + SEQ_BYTES);
  bf16* W1t = (bf16*)(w + SEQ_BYTES + XWC_BYTES);
  bf16* U1t = W1t + 512 * 128;
  bf16* W2t = U1t + 512 * 512;
  bf16* U2t = W2t + 512 * 512;
  bf16* W3t = U2t + 512 * 512;
  bf16* U3t = W3t + 512 * 512;
  bf16* W4t = U3t + 512 * 512;
  bf16* U4t = W4t + 512 * 512;

  convert_weight<<<(512 * 128) / 256, 256, 0, stream>>>(W1, W1t, 100, 128, 512);
  convert_weight<<<(512 * 512) / 256, 256, 0, stream>>>(U1, U1t, 512, 512, 512);
  convert_weight<<<(512 * 512) / 256, 256, 0, stream>>>(W2, W2t, 512, 512, 512);
  convert_weight<<<(512 * 512) / 256, 256, 0, stream>>>(U2, U2t, 512, 512, 512);
  convert_weight<<<(512 * 512) / 256, 256, 0, stream>>>(W3, W3t, 512, 512, 512);
  convert_weight<<<(512 * 512) / 256, 256, 0, stream>>>(U3, U3t, 512, 512, 512);
  convert_weight<<<(512 * 512) / 256, 256, 0, stream>>>(W4, W4t, 512, 512, 512);
  convert_weight<<<(512 * 512) / 256, 256, 0, stream>>>(U4, U4t, 512, 512, 512);

  const bf16* Wt[4] = {W1t, W2t, W3t, W4t};
  const bf16* Us[4] = {U1t, U2t, U3t, U4t};
  const float* bs[4] = {b1, b2, b3, b4};

  for (int layer = 0; layer < 4; layer++) {
    for (int c = 0; c < NC_; c++) {
      if (layer == 0)
        gemm1_embed<<<dim3(TC_ * 16, 4), 256, 0, stream>>>(tokens, emb, W1t, XWC, c * TC_);
      else
        gemm_bf16<<<dim3(TC_ * B_ / 128, 4), 256, 0, stream>>>(
            SEQ + (size_t)c * TC_ * B_ * H_, Wt[layer], XWC, H_);
      rnn_chunk<<<B_ / ROWS_, 1024, 0, stream>>>(XWC, Us[layer], bs[layer], SEQ, c * TC_, c == 0);
    }
  }

  head_kernel<<<B_ / 4, 256, 0, stream>>>(SEQ, Wo, bo, out);
}

// Round 4
// 1576.982 us; speedup vs baseline: 5.2991x; 5.2991x over previous
//
#include <hip/hip_runtime.h>

typedef __bf16 bf16;
typedef bf16 bf16x8 __attribute__((ext_vector_type(8)));
typedef float f32x4 __attribute__((ext_vector_type(4)));
typedef unsigned long u64x2 __attribute__((ext_vector_type(2)));

#define AS1 __attribute__((address_space(1)))
#define AS3 __attribute__((address_space(3)))

#define B_ 2048
#define T_ 80
#define E_ 100
#define H_ 512
#define TC_ 16              // time-chunk
#define NC_ (T_ / TC_)      // 5 chunks
#define ROWS_ 16            // batch rows per rnn block

// SEQ is TIME-MAJOR: seq[(t*B_ + b)*H_ + h]
// U fp8 packed layout: for col n, k -> byte n*512 + (k>>6)*64 + ((k>>3)&3)*16 + ((k>>5)&1)*8 + (k&7)
//   => a lane's dwordx4 at n*512 + kk2*64 + q*16 holds A-chunk kk=2*kk2 (.x) and kk=2*kk2+1 (.y)

__device__ __forceinline__ float fast_tanh(float x) {
  float e = exp2f(x * 2.8853900817779268f);  // e^{2x}
  return 1.f - 2.f * __builtin_amdgcn_rcpf(e + 1.f);
}

__device__ __forceinline__ unsigned char to_fp8(float v) {
  return (unsigned char)(__builtin_amdgcn_cvt_pk_fp8_f32(v, v, 0, false) & 0xff);
}

// pack 8 floats -> 8 fp8 bytes (long)
__device__ __forceinline__ long pack_fp8x8(const float* f) {
  int w0 = __builtin_amdgcn_cvt_pk_fp8_f32(f[0], f[1], 0, false);
  w0 = __builtin_amdgcn_cvt_pk_fp8_f32(f[2], f[3], w0, true);
  int w1 = __builtin_amdgcn_cvt_pk_fp8_f32(f[4], f[5], 0, false);
  w1 = __builtin_amdgcn_cvt_pk_fp8_f32(f[6], f[7], w1, true);
  return (long)(((unsigned long)(unsigned)w1 << 32) | (unsigned)w0);
}

// dst[n*Kp + k] = k<K ? src[k*N + n] : 0   (transpose to [N][Kp], bf16, zero-pad K)
__global__ void convert_weight(const float* __restrict__ src, bf16* __restrict__ dst,
                               int K, int Kp, int N) {
  int idx = blockIdx.x * 256 + threadIdx.x;
  if (idx >= N * Kp) return;
  int n = idx / Kp, k = idx - n * Kp;
  float v = (k < K) ? src[(long)k * N + n] : 0.f;
  dst[idx] = (bf16)v;
}

// U[512x512] fp32 -> fp8 e4m3, scaled by 2^6, packed layout above.
// thread: c = idx>>9 (k-octet), n = idx&511; 8 coalesced src reads, one 8B dst write.
__global__ void convert_u_fp8(const float* __restrict__ src, unsigned char* __restrict__ dst) {
  int idx = blockIdx.x * 256 + threadIdx.x;
  int c = idx >> 9, n = idx & 511;
  float f[8];
#pragma unroll
  for (int j = 0; j < 8; j++) f[j] = src[(long)(c * 8 + j) * H_ + n] * 64.f;
  int k0 = c * 8;
  long off = (long)n * 512 + (k0 >> 6) * 64 + ((k0 >> 3) & 3) * 16 + ((k0 >> 5) & 1) * 8;
  *(long*)(dst + off) = pack_fp8x8(f);
}

// C[128-row tile] = A @ Bt^T; A pre-offset to chunk start. Grid (TC_*B_/128, 4), 256 thr.
__global__ __launch_bounds__(256) void gemm_bf16(
    const bf16* __restrict__ A, const bf16* __restrict__ Bt, bf16* __restrict__ C, int K) {
  __shared__ bf16 As[128 * 32];
  __shared__ bf16 Bs[128 * 32];
  const int tid = threadIdx.x;
  const int wave = tid >> 6, lane = tid & 63;
  const int l = lane & 15, q = lane >> 4;
  const long m0 = (long)blockIdx.x * 128;
  const int n0 = blockIdx.y * 128;
  const int wm = (wave >> 1) * 64, wn = (wave & 1) * 64;

  f32x4 acc[4][4] = {};

  const int e0 = tid, e1 = 256 + tid;
  const int r0 = e0 >> 2, c0 = e0 & 3;
  const int r1 = e1 >> 2, c1 = e1 & 3;
  const int s0 = c0 ^ (r0 & 3) ^ ((r0 >> 2) & 3);
  const int s1 = c1 ^ (r1 & 3) ^ ((r1 >> 2) & 3);
  const int swr = q ^ (l & 3) ^ ((l >> 2) & 3);

  const bf16* A0 = A + (m0 + r0) * K + s0 * 8;
  const bf16* A1 = A + (m0 + r1) * K + s1 * 8;
  const bf16* B0 = Bt + (long)(n0 + r0) * K + s0 * 8;
  const bf16* B1 = Bt + (long)(n0 + r1) * K + s1 * 8;
  bf16* AsW0 = As + (wave * 64) * 8;
  bf16* AsW1 = As + (256 + wave * 64) * 8;
  bf16* BsW0 = Bs + (wave * 64) * 8;
  bf16* BsW1 = Bs + (256 + wave * 64) * 8;

  for (int k0 = 0; k0 < K; k0 += 32) {
    __builtin_amdgcn_global_load_lds((const AS1 void*)(A0 + k0), (AS3 void*)AsW0, 16, 0, 0);
    __builtin_amdgcn_global_load_lds((const AS1 void*)(A1 + k0), (AS3 void*)AsW1, 16, 0, 0);
    __builtin_amdgcn_global_load_lds((const AS1 void*)(B0 + k0), (AS3 void*)BsW0, 16, 0, 0);
    __builtin_amdgcn_global_load_lds((const AS1 void*)(B1 + k0), (AS3 void*)BsW1, 16, 0, 0);
    __syncthreads();
    bf16x8 af[4], bfm[4];
#pragma unroll
    for (int i = 0; i < 4; i++) {
      af[i]  = *(const bf16x8*)(As + (wm + i * 16 + l) * 32 + swr * 8);
      bfm[i] = *(const bf16x8*)(Bs + (wn + i * 16 + l) * 32 + swr * 8);
    }
#pragma unroll
    for (int i = 0; i < 4; i++)
#pragma unroll
      for (int j = 0; j < 4; j++)
        acc[i][j] = __builtin_amdgcn_mfma_f32_16x16x32_bf16(af[i], bfm[j], acc[i][j], 0, 0, 0);
    __syncthreads();
  }
#pragma unroll
  for (int i = 0; i < 4; i++)
#pragma unroll
    for (int j = 0; j < 4; j++)
#pragma unroll
      for (int r = 0; r < 4; r++)
        C[(m0 + wm + i * 16 + q * 4 + r) * (long)H_ + n0 + wn + j * 16 + l] =
            (bf16)acc[i][j][r];
}

// Layer-1 GEMM with fused embedding gather: C = emb[tokens] @ W1 (K padded to 128).
__global__ __launch_bounds__(256) void gemm1_embed(
    const int* __restrict__ tokens, const float* __restrict__ emb,
    const bf16* __restrict__ Bt, bf16* __restrict__ xwc, int t0) {
  __shared__ bf16 As[128 * 32];
  __shared__ bf16 Bs[128 * 32];
  __shared__ int stok[128];
  const int tid = threadIdx.x;
  const int wave = tid >> 6, lane = tid & 63;
  const int l = lane & 15, q = lane >> 4;
  const int trow = blockIdx.x >> 4;
  const int b0 = (blockIdx.x & 15) * 128;
  const int t = t0 + trow;
  const int n0 = blockIdx.y * 128;
  const int wm = (wave >> 1) * 64, wn = (wave & 1) * 64;
  const int K = 128;

  if (tid < 128) stok[tid] = tokens[(b0 + tid) * T_ + t];
  __syncthreads();

  f32x4 acc[4][4] = {};

  const int e0 = tid, e1 = 256 + tid;
  const int r0 = e0 >> 2, c0 = e0 & 3;
  const int r1 = e1 >> 2, c1 = e1 & 3;
  const int s0 = c0 ^ (r0 & 3) ^ ((r0 >> 2) & 3);
  const int s1 = c1 ^ (r1 & 3) ^ ((r1 >> 2) & 3);
  const int swr = q ^ (l & 3) ^ ((l >> 2) & 3);

  const bf16* B0 = Bt + (long)(n0 + r0) * K + s0 * 8;
  const bf16* B1 = Bt + (long)(n0 + r1) * K + s1 * 8;
  bf16* BsW0 = Bs + (wave * 64) * 8;
  bf16* BsW1 = Bs + (256 + wave * 64) * 8;

  const int ar = tid >> 1, hh = tid & 1;
  const int asw = (ar & 3) ^ ((ar >> 2) & 3);
  const float* er = emb + (long)stok[ar] * E_;

  for (int k0 = 0; k0 < K; k0 += 32) {
    __builtin_amdgcn_global_load_lds((const AS1 void*)(B0 + k0), (AS3 void*)BsW0, 16, 0, 0);
    __builtin_amdgcn_global_load_lds((const AS1 void*)(B1 + k0), (AS3 void*)BsW1, 16, 0, 0);
    bf16x8 v[2];
#pragma unroll
    for (int cch = 0; cch < 2; cch++) {
      int kb = k0 + hh * 16 + cch * 8;
#pragma unroll
      for (int j = 0; j < 8; j++) {
        int k = kb + j;
        v[cch][j] = (bf16)((k < E_) ? er[k] : 0.f);
      }
    }
    *(bf16x8*)(As + ar * 32 + ((2 * hh + 0) ^ asw) * 8) = v[0];
    *(bf16x8*)(As + ar * 32 + ((2 * hh + 1) ^ asw) * 8) = v[1];
    __syncthreads();
    bf16x8 af[4], bfm[4];
#pragma unroll
    for (int i = 0; i < 4; i++) {
      af[i]  = *(const bf16x8*)(As + (wm + i * 16 + l) * 32 + swr * 8);
      bfm[i] = *(const bf16x8*)(Bs + (wn + i * 16 + l) * 32 + swr * 8);
    }
#pragma unroll
    for (int i = 0; i < 4; i++)
#pragma unroll
      for (int j = 0; j < 4; j++)
        acc[i][j] = __builtin_amdgcn_mfma_f32_16x16x32_bf16(af[i], bfm[j], acc[i][j], 0, 0, 0);
    __syncthreads();
  }
  bf16* C = xwc + ((long)trow * B_ + b0) * H_;
#pragma unroll
  for (int i = 0; i < 4; i++)
#pragma unroll
    for (int j = 0; j < 4; j++)
#pragma unroll
      for (int r = 0; r < 4; r++)
        C[(long)(wm + i * 16 + q * 4 + r) * H_ + n0 + wn + j * 16 + l] =
            (bf16)acc[i][j][r];
}

// Recurrent chunk: 128 blocks x 512 thr; block = 16 batch rows x 512 cols, 8 waves
// each 16 rows x 64 cols. U streamed fp8 from L2 (dwordx4, reg-pipelined dist 2);
// h in fp8 LDS (A-operand); xw bf16 async-staged (4 bufs, dist 2); seq stores
// coalesced via bf16 LDS staging. LDS 91.5 KB -> 1 block/CU.
__global__ __launch_bounds__(512) void rnn_chunk(
    const bf16* __restrict__ xwc, const unsigned char* __restrict__ U8,
    const float* __restrict__ bias, bf16* __restrict__ seq, int t0, int first) {
  __shared__ long hls8_[ROWS_ * 65];          // 16 rows x 520 B fp8 h  (8.3 KB)
  __shared__ bf16 xws[4 * ROWS_ * 520];       // 4-buf xw staging       (66.6 KB)
  __shared__ bf16 hstg[ROWS_ * 520];          // bf16 h for seq stores  (16.6 KB)
  char* hls8 = (char*)hls8_;
  const int tid = threadIdx.x;
  const int wave = tid >> 6, lane = tid & 63;
  const int l = lane & 15, q = lane >> 4;
  const int ws = wave;                        // col-slice: 64 cols
  const int b0 = blockIdx.x * ROWS_;

  // init h_{t0-1}: rows 2*wave, 2*wave+1; scale by 2^4, pack fp8, ds_write_b64
  {
    const bf16* hsrc = seq + ((long)(t0 - 1) * B_ + b0) * H_;
#pragma unroll
    for (int rr = 0; rr < 2; rr++) {
      int m = wave * 2 + rr;
      long pk = 0;
      if (!first) {
        bf16x8 v = *(const bf16x8*)(hsrc + (long)m * H_ + lane * 8);
        float f[8];
#pragma unroll
        for (int j = 0; j < 8; j++) f[j] = (float)v[j] * 16.f;
        pk = pack_fp8x8(f);
      }
      *(long*)(hls8 + m * 520 + lane * 8) = pk;
    }
  }

  float bb[4];
#pragma unroll
  for (int nt = 0; nt < 4; nt++) bb[nt] = bias[ws * 64 + nt * 16 + l];

  // async xw prefetch: wave issues rows {2*wave, 2*wave+1}; row = 1024B contiguous
  auto prefetch = [&](int tl) {
    int buf = tl & 3;
#pragma unroll
    for (int rr = 0; rr < 2; rr++) {
      int row = wave * 2 + rr;
      __builtin_amdgcn_global_load_lds(
          (const AS1 void*)(xwc + ((long)tl * B_ + b0 + row) * H_ + lane * 8),
          (AS3 void*)(xws + (buf * ROWS_ + row) * 520), 16, 0, 0);
    }
  };

  prefetch(0);
  prefetch(1);
  __syncthreads();  // drains vmcnt: xws bufs 0,1 ready, hls8 init visible

  const char* hb8 = hls8 + l * 520 + q * 8;
  const unsigned char* Ub = U8 + (long)(ws * 64 + l) * 512 + q * 16;

  for (int tl = 0; tl < TC_; tl++) {
    f32x4 acc[4] = {};
    // h_prev @ U in fp8; B loads dwordx4 (2 K-chunks each), pipelined dist 2
    u64x2 bfr[2][4];
#pragma unroll
    for (int nt = 0; nt < 4; nt++) bfr[0][nt] = *(const u64x2*)(Ub + nt * 16 * 512);
#pragma unroll
    for (int nt = 0; nt < 4; nt++) bfr[1][nt] = *(const u64x2*)(Ub + nt * 16 * 512 + 64);
#pragma unroll
    for (int kk2 = 0; kk2 < 8; kk2++) {
      const int cur = kk2 & 1;
      long a0 = *(const long*)(hb8 + kk2 * 64);
      long a1 = *(const long*)(hb8 + kk2 * 64 + 32);
#pragma unroll
      for (int nt = 0; nt < 4; nt++)
        acc[nt] = __builtin_amdgcn_mfma_f32_16x16x32_fp8_fp8(a0, (long)bfr[cur][nt].x,
                                                             acc[nt], 0, 0, 0);
#pragma unroll
      for (int nt = 0; nt < 4; nt++)
        acc[nt] = __builtin_amdgcn_mfma_f32_16x16x32_fp8_fp8(a1, (long)bfr[cur][nt].y,
                                                             acc[nt], 0, 0, 0);
      if (kk2 < 6) {
#pragma unroll
        for (int nt = 0; nt < 4; nt++)
          bfr[cur][nt] = *(const u64x2*)(Ub + nt * 16 * 512 + (kk2 + 2) * 64);
      }
    }
    // h = tanh(xw + b + acc * 2^-10)   (xw from LDS, fp32 math)
    const bf16* xr = xws + ((tl & 3) * ROWS_ + q * 4) * 520 + ws * 64 + l;
    float hv[4][4];
#pragma unroll
    for (int nt = 0; nt < 4; nt++)
#pragma unroll
      for (int r = 0; r < 4; r++)
        hv[nt][r] = fast_tanh((float)xr[r * 520 + nt * 16] + bb[nt] +
                              acc[nt][r] * 0.0009765625f);
    __syncthreads();  // barrier1: all hls8/xws reads for step tl done

#pragma unroll
    for (int nt = 0; nt < 4; nt++) {
      int n = ws * 64 + nt * 16 + l;
#pragma unroll
      for (int r = 0; r < 4; r++) {
        int m = q * 4 + r;
        hls8[m * 520 + n] = (char)to_fp8(hv[nt][r] * 16.f);
        hstg[m * 520 + n] = (bf16)hv[nt][r];
      }
    }
    __syncthreads();  // barrier2: hls8/hstg updated

    if (tl + 2 < TC_) prefetch(tl + 2);

    // coalesced seq store: wave stores rows 2*wave, 2*wave+1 (1KB each)
    bf16* sp = seq + ((long)(t0 + tl) * B_ + b0) * H_;
#pragma unroll
    for (int rr = 0; rr < 2; rr++) {
      int m = wave * 2 + rr;
      *(bf16x8*)(sp + (long)m * H_ + lane * 8) =
          *(const bf16x8*)(hstg + m * 520 + lane * 8);
    }
  }
}

// out[b] = sigmoid(dot(seq[(T-1)*B + b, :], Wo) + bo); one wave per row
__global__ __launch_bounds__(256) void head_kernel(
    const bf16* __restrict__ seq, const float* __restrict__ Wo,
    const float* __restrict__ bo, float* __restrict__ out) {
  int wave = threadIdx.x >> 6, lane = threadIdx.x & 63;
  int row = blockIdx.x * 4 + wave;
  const bf16* p = seq + ((long)(T_ - 1) * B_ + row) * H_ + lane * 8;
  bf16x8 v = *(const bf16x8*)p;
  float s = 0.f;
#pragma unroll
  for (int i = 0; i < 8; i++) s += (float)v[i] * Wo[lane * 8 + i];
#pragma unroll
  for (int off = 32; off; off >>= 1) s += __shfl_down(s, off, 64);
  if (lane == 0) {
    float x = s + bo[0];
    out[row] = 1.f / (1.f + exp2f(-x * 1.44269504088896f));
  }
}

extern "C" void kernel_launch(void* const* d_in, const int* in_sizes, int n_in,
                              void* d_out, int out_size, void* d_ws, size_t ws_size,
                              hipStream_t stream) {
  (void)in_sizes; (void)n_in; (void)out_size; (void)ws_size;
  const int*   tokens = (const int*)d_in[0];
  const float* emb = (const float*)d_in[1];
  const float* W1 = (const float*)d_in[2];
  const float* U1 = (const float*)d_in[3];
  const float* b1 = (const float*)d_in[4];
  const float* W2 = (const float*)d_in[5];
  const float* U2 = (const float*)d_in[6];
  const float* b2 = (const float*)d_in[7];
  const float* W3 = (const float*)d_in[8];
  const float* U3 = (const float*)d_in[9];
  const float* b3 = (const float*)d_in[10];
  const float* W4 = (const float*)d_in[11];
  const float* U4 = (const float*)d_in[12];
  const float* b4 = (const float*)d_in[13];
  const float* Wo = (const float*)d_in[14];
  const float* bo = (const float*)d_in[15];
  float* out = (float*)d_out;

  // ws: SEQ (time-major, in-place across layers) | XWC | W-weights bf16 | U-weights fp8
  char* w = (char*)d_ws;
  const size_t SEQ_BYTES = (size_t)T_ * B_ * H_ * 2;   // 160 MB
  const size_t XWC_BYTES = (size_t)TC_ * B_ * H_ * 2;  // 32 MB
  bf16* SEQ = (bf16*)w;
  bf16* XWC = (bf16*)(w + SEQ_BYTES);
  bf16* W1t = (bf16*)(w + SEQ_BYTES + XWC_BYTES);
  bf16* W2t = W1t + 512 * 128;
  bf16* W3t = W2t + 512 * 512;
  bf16* W4t = W3t + 512 * 512;
  unsigned char* U1p = (unsigned char*)(W4t + 512 * 512);
  unsigned char* U2p = U1p + 512 * 512;
  unsigned char* U3p = U2p + 512 * 512;
  unsigned char* U4p = U3p + 512 * 512;

  convert_weight<<<(512 * 128) / 256, 256, 0, stream>>>(W1, W1t, 100, 128, 512);
  convert_weight<<<(512 * 512) / 256, 256, 0, stream>>>(W2, W2t, 512, 512, 512);
  convert_weight<<<(512 * 512) / 256, 256, 0, stream>>>(W3, W3t, 512, 512, 512);
  convert_weight<<<(512 * 512) / 256, 256, 0, stream>>>(W4, W4t, 512, 512, 512);
  convert_u_fp8<<<(512 * 64) / 256, 256, 0, stream>>>(U1, U1p);
  convert_u_fp8<<<(512 * 64) / 256, 256, 0, stream>>>(U2, U2p);
  convert_u_fp8<<<(512 * 64) / 256, 256, 0, stream>>>(U3, U3p);
  convert_u_fp8<<<(512 * 64) / 256, 256, 0, stream>>>(U4, U4p);

  const bf16* Wt[4] = {W1t, W2t, W3t, W4t};
  const unsigned char* Up[4] = {U1p, U2p, U3p, U4p};
  const float* bs[4] = {b1, b2, b3, b4};

  for (int layer = 0; layer < 4; layer++) {
    for (int c = 0; c < NC_; c++) {
      if (layer == 0)
        gemm1_embed<<<dim3(TC_ * 16, 4), 256, 0, stream>>>(tokens, emb, W1t, XWC, c * TC_);
      else
        gemm_bf16<<<dim3(TC_ * B_ / 128, 4), 256, 0, stream>>>(
            SEQ + (size_t)c * TC_ * B_ * H_, Wt[layer], XWC, H_);
      rnn_chunk<<<B_ / ROWS_, 512, 0, stream>>>(XWC, Up[layer], bs[layer], SEQ, c * TC_, c == 0);
    }
  }

  head_kernel<<<B_ / 4, 256, 0, stream>>>(SEQ, Wo, bo, out);
}